// Round 10
// baseline (29.864 us; speedup 1.0000x reference)
//
#include <hip/hip_runtime.h>

// Fasttext: out[b,t,p] = W @ embed[ids[b,t]] + b, masked t < seq_lengths[b]
// VOCAB=200000, E=300, P=128, B=16, S=2048, BS=32768
//
// R10: two-phase to fix the latency-bound random gather.
//  A (ft_gather): valid tokens' embed rows -> compact bf16 ws[32768][304].
//    Row-coalesced: lane = consecutive k within a row (<=2 random rows per
//    instruction vs 64 in R8). Invalid tokens skipped (B masks output).
//  B (ft_gemm): R8's GEMM (64tok x 64col-half blocks, W-half fragment-major
//    in 40KB LDS, grid 1024, 16 waves/CU) but A-fragments read dense from
//    ws -- L3-hot (written this replay), bf16 already (no cvt).
// Fallback to the R8 single-kernel if ws_size too small.

#define E 300
#define P 128
#define S 2048
#define BS 32768
#define TM 64
#define WSR 304                       // ws row stride in bf16 elems (608 B)
#define WS_NEED ((size_t)BS * WSR * 2)

typedef short bf16x8 __attribute__((ext_vector_type(8)));
typedef short bf16x4 __attribute__((ext_vector_type(4)));
typedef float f32x4 __attribute__((ext_vector_type(4)));

__device__ inline unsigned short f32_bf16_fast(float f) {
    unsigned int u = __builtin_bit_cast(unsigned int, f);
    return (unsigned short)((u + 0x8000u) >> 16);
}
__device__ inline bf16x8 cvt8(f32x4 a, f32x4 b) {
    bf16x8 r;
    r[0] = (short)f32_bf16_fast(a[0]); r[1] = (short)f32_bf16_fast(a[1]);
    r[2] = (short)f32_bf16_fast(a[2]); r[3] = (short)f32_bf16_fast(a[3]);
    r[4] = (short)f32_bf16_fast(b[0]); r[5] = (short)f32_bf16_fast(b[1]);
    r[6] = (short)f32_bf16_fast(b[2]); r[7] = (short)f32_bf16_fast(b[3]);
    return r;
}
__device__ inline bf16x4 cvt4(f32x4 a) {
    bf16x4 r;
    r[0] = (short)f32_bf16_fast(a[0]); r[1] = (short)f32_bf16_fast(a[1]);
    r[2] = (short)f32_bf16_fast(a[2]); r[3] = (short)f32_bf16_fast(a[3]);
    return r;
}

// ---------------- Kernel A: row-coalesced gather -> compact bf16 ws ----------
__global__ __launch_bounds__(256) void ft_gather(
    const int* __restrict__ ids, const int* __restrict__ seqlen,
    const float* __restrict__ embed, unsigned short* __restrict__ ws)
{
    const int tid  = threadIdx.x;
    const int tok0 = blockIdx.x * TM;
    const int bi0  = tok0 >> 11;
    const int t0   = tok0 & (S - 1);
    const int sl0  = seqlen[bi0];
    if (sl0 <= t0) return;                    // fully masked: B zeroes output

    __shared__ int sid[TM];
    if (tid < TM) sid[tid] = ids[tok0 + tid];
    __syncthreads();

    // flat = tid + i*256 in [0, 64*75): r = flat/75, c4 = flat%75
    // load embed[sid[r]]*300 + c4*4 (f32x4, coalesced runs of 75 lanes),
    // store ws[(tok0+r)*304 + c4*4] (bf16x4, coalesced).
    #pragma unroll
    for (int i = 0; i < 19; ++i) {
        int flat = tid + i * 256;
        if (flat < 4800) {
            int r  = flat / 75;
            int c4 = flat - r * 75;
            int token = tok0 + r;
            int t = token & (S - 1);
            if (t < sl0) {
                f32x4 v = *(const f32x4*)(embed + (long long)sid[r] * E + c4 * 4);
                *(bf16x4*)(ws + (long long)token * WSR + c4 * 4) = cvt4(v);
            }
        }
    }
}

// ---------------- Kernel B: dense GEMM from ws (L3-hot) ---------------------
__global__ __launch_bounds__(256) void ft_gemm(
    const int* __restrict__ seqlen, const unsigned short* __restrict__ ws,
    const float* __restrict__ Wf, const float* __restrict__ bias,
    float* __restrict__ out)
{
    // W-half, bf16, fragment-major: off(s,ni,fr,kg,h) =
    //   ((s*4+ni)*16+fr)*64 + kg*16 + h*8  -> 40960 B
    __shared__ unsigned char Wl[40960];

    const int tid  = threadIdx.x;
    const int wave = tid >> 6, lane = tid & 63;
    const int fr   = lane & 15, kg = lane >> 4;

    const int tile = blockIdx.x >> 1;
    const int ch   = blockIdx.x & 1;
    const int tok0 = tile * TM;
    const int bi0  = tok0 >> 11;
    const int t0   = tok0 & (S - 1);
    const int sl0  = seqlen[bi0];

    if (sl0 <= t0) {                           // zero 64 tok x our 64-col half
        #pragma unroll
        for (int i = 0; i < 4; ++i) {
            int idx   = tid + i * 256;
            int token = tok0 + (idx >> 4);
            int c     = ch * 64 + (idx & 15) * 4;
            *(f32x4*)(out + (long long)token * P + c) = (f32x4){0.f, 0.f, 0.f, 0.f};
        }
        return;
    }

    // A fragments: dense bf16 from ws (L3-hot). Row is 608 B, 16B-aligned.
    // Invalid tokens in partial tiles read stale/poison -> finite -> masked.
    const int token_a = tok0 + wave * 16 + fr;
    const unsigned short* __restrict__ rp = ws + (long long)token_a * WSR;

    bf16x8 av[10];
    #pragma unroll
    for (int s = 0; s < 9; ++s)
        av[s] = *(const bf16x8*)(rp + s * 32 + kg * 8);
    // tail: k 288..303 within row; kg>=2 (k>=304) pairs with W=0 -> read kg&1
    av[9] = *(const bf16x8*)(rp + 288 + (kg & 1) * 8);

    // stage W rows [ch*64, ch*64+64) -> LDS bf16 fragment-major
    const int R0 = ch * 64;
    #pragma unroll
    for (int i = 0; i < 20; ++i) {
        int g4 = tid + i * 256;
        int r  = g4 / 80;
        int c4 = g4 - r * 80;
        int c0 = c4 * 4;
        f32x4 v = {0.f, 0.f, 0.f, 0.f};
        if (c0 < 300)                           // c0 <= 296: reads 296..299 exact
            v = *(const f32x4*)(Wf + (long long)(R0 + r) * E + c0);
        int s   = c0 >> 5;
        int kgg = (c0 & 31) >> 3;
        int h   = (c0 >> 2) & 1;
        int ni  = r >> 4;
        int fr2 = r & 15;
        int off = (((s * 4 + ni) * 16 + fr2) << 6) + (kgg << 4) + (h << 3);
        *(bf16x4*)(Wl + off) = cvt4(v);
    }
    __syncthreads();

    f32x4 acc[4];
    #pragma unroll
    for (int ni = 0; ni < 4; ++ni) acc[ni] = (f32x4){0.f, 0.f, 0.f, 0.f};

    #pragma unroll
    for (int s = 0; s < 10; ++s) {
        #pragma unroll
        for (int ni = 0; ni < 4; ++ni) {
            bf16x8 bv = *(const bf16x8*)(Wl + ((((s * 4 + ni) * 16 + fr) << 6) + (kg << 4)));
            acc[ni] = __builtin_amdgcn_mfma_f32_16x16x32_bf16(av[s], bv, acc[ni], 0, 0, 0);
        }
    }

    // epilogue: +bias, per-row seq-mask, store
    // C/D layout: col(=W row -> P) = lane&15, row(=token) = (lane>>4)*4 + j
    float bs[4];
    #pragma unroll
    for (int ni = 0; ni < 4; ++ni) bs[ni] = bias[ch * 64 + ni * 16 + fr];

    #pragma unroll
    for (int j = 0; j < 4; ++j) {
        int orow  = wave * 16 + kg * 4 + j;
        int token = tok0 + orow;
        int t     = token & (S - 1);
        bool valid = (t < sl0);
        #pragma unroll
        for (int ni = 0; ni < 4; ++ni) {
            float v = valid ? (acc[ni][j] + bs[ni]) : 0.0f;
            out[(long long)token * P + ch * 64 + ni * 16 + fr] = v;
        }
    }
}

// ---------------- Fallback: R8 single-kernel (known-good 22.7us) ------------
__global__ __launch_bounds__(256) void ft_mono(
    const int* __restrict__ ids, const int* __restrict__ seqlen,
    const float* __restrict__ embed, const float* __restrict__ Wf,
    const float* __restrict__ bias, float* __restrict__ out)
{
    __shared__ unsigned char Wl[40960];
    const int tid  = threadIdx.x;
    const int wave = tid >> 6, lane = tid & 63;
    const int fr   = lane & 15, kg = lane >> 4;
    const int tile = blockIdx.x >> 1;
    const int ch   = blockIdx.x & 1;
    const int tok0 = tile * TM;
    const int bi0  = tok0 >> 11;
    const int t0   = tok0 & (S - 1);
    const int sl0  = seqlen[bi0];

    if (sl0 <= t0) {
        #pragma unroll
        for (int i = 0; i < 4; ++i) {
            int idx   = tid + i * 256;
            int token = tok0 + (idx >> 4);
            int c     = ch * 64 + (idx & 15) * 4;
            *(f32x4*)(out + (long long)token * P + c) = (f32x4){0.f, 0.f, 0.f, 0.f};
        }
        return;
    }

    const int token_a = tok0 + wave * 16 + fr;
    const long long id = ids[token_a];
    const float* __restrict__ rp = embed + id * (long long)E;

    bf16x8 av[10];
    #pragma unroll
    for (int s = 0; s < 9; ++s) {
        const int kb = s * 32 + kg * 8;
        f32x4 f0 = *(const f32x4*)(rp + kb);
        f32x4 f1 = *(const f32x4*)(rp + kb + 4);
        av[s] = cvt8(f0, f1);
    }
    {
        f32x4 z4 = {0.f, 0.f, 0.f, 0.f};
        f32x4 f0 = z4, f1 = z4;
        if (kg == 0)      { f0 = *(const f32x4*)(rp + 288); f1 = *(const f32x4*)(rp + 292); }
        else if (kg == 1) { f0 = *(const f32x4*)(rp + 296); }
        av[9] = cvt8(f0, f1);
    }

    const int R0 = ch * 64;
    #pragma unroll
    for (int i = 0; i < 20; ++i) {
        int g4 = tid + i * 256;
        int r  = g4 / 80;
        int c4 = g4 - r * 80;
        int c0 = c4 * 4;
        f32x4 v = {0.f, 0.f, 0.f, 0.f};
        if (c0 < 300)
            v = *(const f32x4*)(Wf + (long long)(R0 + r) * E + c0);
        int s   = c0 >> 5;
        int kgg = (c0 & 31) >> 3;
        int h   = (c0 >> 2) & 1;
        int ni  = r >> 4;
        int fr2 = r & 15;
        int off = (((s * 4 + ni) * 16 + fr2) << 6) + (kgg << 4) + (h << 3);
        *(bf16x4*)(Wl + off) = cvt4(v);
    }
    __syncthreads();

    f32x4 acc[4];
    #pragma unroll
    for (int ni = 0; ni < 4; ++ni) acc[ni] = (f32x4){0.f, 0.f, 0.f, 0.f};
    #pragma unroll
    for (int s = 0; s < 10; ++s) {
        #pragma unroll
        for (int ni = 0; ni < 4; ++ni) {
            bf16x8 bv = *(const bf16x8*)(Wl + ((((s * 4 + ni) * 16 + fr) << 6) + (kg << 4)));
            acc[ni] = __builtin_amdgcn_mfma_f32_16x16x32_bf16(av[s], bv, acc[ni], 0, 0, 0);
        }
    }

    float bs[4];
    #pragma unroll
    for (int ni = 0; ni < 4; ++ni) bs[ni] = bias[ch * 64 + ni * 16 + fr];
    #pragma unroll
    for (int j = 0; j < 4; ++j) {
        int orow  = wave * 16 + kg * 4 + j;
        int token = tok0 + orow;
        int t     = token & (S - 1);
        bool valid = (t < sl0);
        #pragma unroll
        for (int ni = 0; ni < 4; ++ni) {
            float v = valid ? (acc[ni][j] + bs[ni]) : 0.0f;
            out[(long long)token * P + ch * 64 + ni * 16 + fr] = v;
        }
    }
}

extern "C" void kernel_launch(void* const* d_in, const int* in_sizes, int n_in,
                              void* d_out, int out_size, void* d_ws, size_t ws_size,
                              hipStream_t stream) {
    const int*   ids    = (const int*)d_in[0];
    const int*   sl     = (const int*)d_in[1];
    const float* embed  = (const float*)d_in[2];
    const float* W      = (const float*)d_in[3];
    const float* bias   = (const float*)d_in[4];
    float*       out    = (float*)d_out;

    if (ws_size >= WS_NEED) {
        unsigned short* ws = (unsigned short*)d_ws;
        ft_gather<<<BS / TM, 256, 0, stream>>>(ids, sl, embed, ws);
        ft_gemm<<<(BS / TM) * 2, 256, 0, stream>>>(sl, ws, W, bias, out);
    } else {
        ft_mono<<<(BS / TM) * 2, 256, 0, stream>>>(ids, sl, embed, W, bias, out);
    }
}

// Round 12
// 24.321 us; speedup vs baseline: 1.2279x; 1.2279x over previous
//
#include <hip/hip_runtime.h>

// Fasttext: out[b,t,p] = W @ embed[ids[b,t]] + b, masked t < seq_lengths[b]
// VOCAB=200000, E=300, P=128, B=16, S=2048, BS=32768
//
// R11 (resubmit after infra failure): dup=1 gather at R8's occupancy,
// single kernel. TM=32, grid 1024, block = 32 tok x FULL 128 cols, 256 thr
// / 4 waves. Two passes over col-halves reuse ONE 40KB W-half LDS buffer
// (stage rows[0:64) -> MFMA + epilogue cols 0-63 -> barrier -> stage rows
// [64:128) -> cols 64-127). A fragments av[10] gathered ONCE (19 hoisted
// loads/lane), held across passes. 4 blocks/CU -> 16 waves/CU -> in-flight
// gather = R8's, but HBM gather traffic halves (39 -> 20MB). ids load
// hoisted above the mask branch. Wave = 16 tok x 32 cols per pass (acc[2]).

#define E 300
#define P 128
#define S 2048
#define BS 32768
#define TM 32             // tokens per block tile

typedef short bf16x8 __attribute__((ext_vector_type(8)));
typedef short bf16x4 __attribute__((ext_vector_type(4)));
typedef float f32x4 __attribute__((ext_vector_type(4)));

// round-nearest (ties up) f32->bf16: 2 VALU/elem
__device__ inline unsigned short f32_bf16_fast(float f) {
    unsigned int u = __builtin_bit_cast(unsigned int, f);
    return (unsigned short)((u + 0x8000u) >> 16);
}
__device__ inline bf16x8 cvt8(f32x4 a, f32x4 b) {
    bf16x8 r;
    r[0] = (short)f32_bf16_fast(a[0]); r[1] = (short)f32_bf16_fast(a[1]);
    r[2] = (short)f32_bf16_fast(a[2]); r[3] = (short)f32_bf16_fast(a[3]);
    r[4] = (short)f32_bf16_fast(b[0]); r[5] = (short)f32_bf16_fast(b[1]);
    r[6] = (short)f32_bf16_fast(b[2]); r[7] = (short)f32_bf16_fast(b[3]);
    return r;
}
__device__ inline bf16x4 cvt4(f32x4 a) {
    bf16x4 r;
    r[0] = (short)f32_bf16_fast(a[0]); r[1] = (short)f32_bf16_fast(a[1]);
    r[2] = (short)f32_bf16_fast(a[2]); r[3] = (short)f32_bf16_fast(a[3]);
    return r;
}

__global__ __launch_bounds__(256, 4) void ft_main(
    const int* __restrict__ ids, const int* __restrict__ seqlen,
    const float* __restrict__ embed, const float* __restrict__ Wf,
    const float* __restrict__ bias, float* __restrict__ out)
{
    // W-half (64 rows x 320 k), bf16, fragment-major:
    //   off(s, nq, fr, kg, h) = ((s*4+nq)*16+fr)*64 + kg*16 + h*8  -> 40960 B
    __shared__ unsigned char Wl[40960];

    const int tid  = threadIdx.x;
    const int wave = tid >> 6, lane = tid & 63;
    const int fr   = lane & 15, kg = lane >> 4;
    const int wm   = wave >> 1;                 // token-group (0/1)
    const int wn   = wave & 1;                  // 32-col subgroup within pass

    const int tok0 = blockIdx.x * TM;
    const int bi0  = tok0 >> 11;                // batch (32 | 2048)
    const int t0   = tok0 & (S - 1);

    // hoist: issue this lane's id load before the mask branch (addr valid)
    const int token_a = tok0 + wm * 16 + fr;
    const int id = ids[token_a];
    const int sl0 = seqlen[bi0];

    // ---- full-tile mask early-out: zero 32 tok x 128 cols (16KB) ----
    if (sl0 <= t0) {
        f32x4* o = (f32x4*)(out + (long long)tok0 * P);
        f32x4 z = {0.f, 0.f, 0.f, 0.f};
        #pragma unroll
        for (int i = 0; i < 4; ++i)
            o[tid + i * 256] = z;
        return;
    }

    // ---- A: gather this lane's row fragments (19 independent loads) ----
    const float* __restrict__ rp = embed + (long long)id * E;

    bf16x8 av[10];
    #pragma unroll
    for (int s = 0; s < 9; ++s) {
        const int kb = s * 32 + kg * 8;         // <= 280; ends 287 < 300
        f32x4 f0 = *(const f32x4*)(rp + kb);
        f32x4 f1 = *(const f32x4*)(rp + kb + 4);
        av[s] = cvt8(f0, f1);
    }
    {   // tail: valid k 288..299, exact bounds; kg>=2 lanes -> zero A
        f32x4 z4 = {0.f, 0.f, 0.f, 0.f};
        f32x4 f0 = z4, f1 = z4;
        if (kg == 0)      { f0 = *(const f32x4*)(rp + 288); f1 = *(const f32x4*)(rp + 292); }
        else if (kg == 1) { f0 = *(const f32x4*)(rp + 296); }
        av[9] = cvt8(f0, f1);
    }

    // ---- two passes over col-halves, reusing the 40KB W LDS buffer ----
    #pragma unroll 1
    for (int p = 0; p < 2; ++p) {
        // stage W rows [p*64, p*64+64) -> LDS fragment-major
        const int R0 = p * 64;
        #pragma unroll 5
        for (int i = 0; i < 20; ++i) {
            int g4 = tid + i * 256;             // [0, 5120) quads
            int r  = g4 / 80;
            int c4 = g4 - r * 80;
            int c0 = c4 * 4;                    // {0,4,...,316}
            f32x4 v = {0.f, 0.f, 0.f, 0.f};
            if (c0 < 300)                       // c0 <= 296: reads 296..299 exact
                v = *(const f32x4*)(Wf + (long long)(R0 + r) * E + c0);
            int s   = c0 >> 5;
            int kgg = (c0 & 31) >> 3;
            int h   = (c0 >> 2) & 1;
            int nq  = r >> 4;
            int fr2 = r & 15;
            int off = (((s * 4 + nq) * 16 + fr2) << 6) + (kgg << 4) + (h << 3);
            *(bf16x4*)(Wl + off) = cvt4(v);
        }
        __syncthreads();

        // MFMA: 10 k-steps x 2 ni (this wave's 32 cols of the pass half)
        f32x4 acc[2];
        acc[0] = (f32x4){0.f, 0.f, 0.f, 0.f};
        acc[1] = (f32x4){0.f, 0.f, 0.f, 0.f};

        #pragma unroll
        for (int s = 0; s < 10; ++s) {
            #pragma unroll
            for (int ni = 0; ni < 2; ++ni) {
                int nq = wn * 2 + ni;
                bf16x8 bv = *(const bf16x8*)(Wl + ((((s * 4 + nq) * 16 + fr) << 6) + (kg << 4)));
                acc[ni] = __builtin_amdgcn_mfma_f32_16x16x32_bf16(av[s], bv, acc[ni], 0, 0, 0);
            }
        }

        // epilogue for this pass: +bias, per-row seq-mask, store
        // C/D layout: col(=W row -> P) = lane&15, row(=token) = (lane>>4)*4 + j
        const int cbase = p * 64 + wn * 32;
        float bs0 = bias[cbase + fr];
        float bs1 = bias[cbase + 16 + fr];

        #pragma unroll
        for (int j = 0; j < 4; ++j) {
            int orow  = wm * 16 + kg * 4 + j;
            int token = tok0 + orow;
            int t     = token & (S - 1);
            bool valid = (t < sl0);
            float v0 = valid ? (acc[0][j] + bs0) : 0.0f;
            float v1 = valid ? (acc[1][j] + bs1) : 0.0f;
            out[(long long)token * P + cbase + fr]      = v0;
            out[(long long)token * P + cbase + 16 + fr] = v1;
        }

        if (p == 0) __syncthreads();            // all waves done reading Wl
    }
}

extern "C" void kernel_launch(void* const* d_in, const int* in_sizes, int n_in,
                              void* d_out, int out_size, void* d_ws, size_t ws_size,
                              hipStream_t stream) {
    const int*   ids    = (const int*)d_in[0];
    const int*   sl     = (const int*)d_in[1];
    const float* embed  = (const float*)d_in[2];
    const float* W      = (const float*)d_in[3];
    const float* bias   = (const float*)d_in[4];
    float*       out    = (float*)d_out;

    ft_main<<<BS / TM, 256, 0, stream>>>(ids, sl, embed, W, bias, out);
}

// Round 13
// 20.137 us; speedup vs baseline: 1.4830x; 1.2078x over previous
//
#include <hip/hip_runtime.h>

// Fasttext: out[b,t,p] = W @ embed[ids[b,t]] + b, masked t < seq_lengths[b]
// VOCAB=200000, E=300, P=128, B=16, S=2048, BS=32768
//
// R13 = R8 (best: 22.7us) + XCD-pairing blockIdx swizzle + ids-load hoist.
// R8's two col-half blocks of a tile gather the SAME 64 embed rows; under
// round-robin dispatch they land on different XCDs, so the duplicate read
// hits L3. Swizzle d=grp*16+sub -> tile=grp*8+(sub&7), ch=sub>>3 puts both
// halves on the SAME XCD (same dispatch-slot mod 8) -> duplicate gather
// becomes an L2 hit. Everything else identical to R8: 64tok x 64col-half
// blocks, W-half fragment-major in 40KB LDS (conflict-free ds_read_b128),
// A-gather hoisted (19 independent loads/lane), exact-bounds tails.

#define E 300
#define P 128
#define S 2048
#define BS 32768
#define TM 64           // tokens per block tile

typedef short bf16x8 __attribute__((ext_vector_type(8)));
typedef short bf16x4 __attribute__((ext_vector_type(4)));
typedef float f32x4 __attribute__((ext_vector_type(4)));

// round-nearest (ties up) f32->bf16: 2 VALU/elem
__device__ inline unsigned short f32_bf16_fast(float f) {
    unsigned int u = __builtin_bit_cast(unsigned int, f);
    return (unsigned short)((u + 0x8000u) >> 16);
}
__device__ inline bf16x8 cvt8(f32x4 a, f32x4 b) {
    bf16x8 r;
    r[0] = (short)f32_bf16_fast(a[0]); r[1] = (short)f32_bf16_fast(a[1]);
    r[2] = (short)f32_bf16_fast(a[2]); r[3] = (short)f32_bf16_fast(a[3]);
    r[4] = (short)f32_bf16_fast(b[0]); r[5] = (short)f32_bf16_fast(b[1]);
    r[6] = (short)f32_bf16_fast(b[2]); r[7] = (short)f32_bf16_fast(b[3]);
    return r;
}
__device__ inline bf16x4 cvt4(f32x4 a) {
    bf16x4 r;
    r[0] = (short)f32_bf16_fast(a[0]); r[1] = (short)f32_bf16_fast(a[1]);
    r[2] = (short)f32_bf16_fast(a[2]); r[3] = (short)f32_bf16_fast(a[3]);
    return r;
}

__global__ __launch_bounds__(256) void ft_main(
    const int* __restrict__ ids, const int* __restrict__ seqlen,
    const float* __restrict__ embed, const float* __restrict__ Wf,
    const float* __restrict__ bias, float* __restrict__ out)
{
    // W-half, bf16, fragment-major: offset((s,ni,fr,kg,h)) =
    //   ((s*4+ni)*16+fr)*64 + kg*16 + h*8   -> 10*4*16*64 = 40960 B
    __shared__ unsigned char Wl[40960];

    const int tid  = threadIdx.x;
    const int wave = tid >> 6, lane = tid & 63;
    const int fr   = lane & 15, kg = lane >> 4;

    // XCD-pairing swizzle: both col-halves of a tile share dispatch slot mod 8
    const int bid  = blockIdx.x;                // [0, 1024)
    const int grp  = bid >> 4;                  // [0, 64)
    const int sub  = bid & 15;                  // [0, 16)
    const int tile = grp * 8 + (sub & 7);       // [0, 512)
    const int ch   = sub >> 3;                  // 0/1: which 64-col half of P

    const int tok0 = tile * TM;
    const int bi0  = tok0 >> 11;                // batch (64 | 2048)
    const int t0   = tok0 & (S - 1);

    // hoist: issue this lane's id load before the mask branch (addr valid)
    const int token_a = tok0 + wave * 16 + fr;
    const int id  = ids[token_a];
    const int sl0 = seqlen[bi0];

    // ---- full-tile mask early-out: zero 64 tokens x our 64-col half ----
    if (sl0 <= t0) {
        #pragma unroll
        for (int i = 0; i < 4; ++i) {
            int idx   = tid + i * 256;          // [0,1024): 64 tok x 16 col-quads
            int token = tok0 + (idx >> 4);
            int c     = ch * 64 + (idx & 15) * 4;
            *(f32x4*)(out + (long long)token * P + c) = (f32x4){0.f, 0.f, 0.f, 0.f};
        }
        return;
    }

    // ---- A: issue the gather early (independent of LDS staging) ----
    const float* __restrict__ rp = embed + (long long)id * E;

    bf16x8 av[10];
    #pragma unroll
    for (int s = 0; s < 9; ++s) {
        const int kb = s * 32 + kg * 8;         // <= 280; ends 287 < 300
        f32x4 f0 = *(const f32x4*)(rp + kb);
        f32x4 f1 = *(const f32x4*)(rp + kb + 4);
        av[s] = cvt8(f0, f1);
    }
    {   // tail: valid k 288..299, exact bounds
        f32x4 z4 = {0.f, 0.f, 0.f, 0.f};
        f32x4 f0 = z4, f1 = z4;
        if (kg == 0)      { f0 = *(const f32x4*)(rp + 288); f1 = *(const f32x4*)(rp + 292); }
        else if (kg == 1) { f0 = *(const f32x4*)(rp + 296); }
        av[9] = cvt8(f0, f1);
    }

    // ---- stage W rows [ch*64, ch*64+64) -> LDS bf16 fragment-major ----
    // flat g4 in [0,5120): r = g4/80, c0 = (g4%80)*4 in [0,320); zero-pad c0>=300.
    const int R0 = ch * 64;
    #pragma unroll
    for (int i = 0; i < 20; ++i) {
        int g4 = tid + i * 256;
        int r  = g4 / 80;
        int c4 = g4 - r * 80;
        int c0 = c4 * 4;
        f32x4 v = {0.f, 0.f, 0.f, 0.f};
        if (c0 < 300)                            // c0 <= 296 -> reads 296..299, exact
            v = *(const f32x4*)(Wf + (long long)(R0 + r) * E + c0);
        int s   = c0 >> 5;
        int kgg = (c0 & 31) >> 3;
        int h   = (c0 >> 2) & 1;
        int ni  = r >> 4;
        int fr2 = r & 15;
        int off = (((s * 4 + ni) * 16 + fr2) << 6) + (kgg << 4) + (h << 3);
        *(bf16x4*)(Wl + off) = cvt4(v);
    }
    __syncthreads();

    // ---- MFMA: 10 k-steps x 4 ni, B from LDS (conflict-free b128) ----
    f32x4 acc[4];
    #pragma unroll
    for (int ni = 0; ni < 4; ++ni) acc[ni] = (f32x4){0.f, 0.f, 0.f, 0.f};

    #pragma unroll
    for (int s = 0; s < 10; ++s) {
        #pragma unroll
        for (int ni = 0; ni < 4; ++ni) {
            bf16x8 bv = *(const bf16x8*)(Wl + ((((s * 4 + ni) * 16 + fr) << 6) + (kg << 4)));
            acc[ni] = __builtin_amdgcn_mfma_f32_16x16x32_bf16(av[s], bv, acc[ni], 0, 0, 0);
        }
    }

    // ---- epilogue: +bias, per-row seq-mask, store ----
    // C/D layout: col(=W row -> P) = lane&15, row(=token) = (lane>>4)*4 + j
    float bs[4];
    #pragma unroll
    for (int ni = 0; ni < 4; ++ni) bs[ni] = bias[ch * 64 + ni * 16 + fr];

    #pragma unroll
    for (int j = 0; j < 4; ++j) {
        int orow  = wave * 16 + kg * 4 + j;
        int token = tok0 + orow;
        int t     = token & (S - 1);
        bool valid = (t < sl0);
        #pragma unroll
        for (int ni = 0; ni < 4; ++ni) {
            float v = valid ? (acc[ni][j] + bs[ni]) : 0.0f;
            out[(long long)token * P + ch * 64 + ni * 16 + fr] = v;
        }
    }
}

extern "C" void kernel_launch(void* const* d_in, const int* in_sizes, int n_in,
                              void* d_out, int out_size, void* d_ws, size_t ws_size,
                              hipStream_t stream) {
    const int*   ids    = (const int*)d_in[0];
    const int*   sl     = (const int*)d_in[1];
    const float* embed  = (const float*)d_in[2];
    const float* W      = (const float*)d_in[3];
    const float* bias   = (const float*)d_in[4];
    float*       out    = (float*)d_out;

    ft_main<<<(BS / TM) * 2, 256, 0, stream>>>(ids, sl, embed, W, bias, out);
}

// Round 14
// 19.955 us; speedup vs baseline: 1.4965x; 1.0091x over previous
//
#include <hip/hip_runtime.h>

// Fasttext: out[b,t,p] = W @ embed[ids[b,t]] + b, masked t < seq_lengths[b]
// VOCAB=200000, E=300, P=128, B=16, S=2048, BS=32768
//
// R15 = R13 (20.1us) + mask-aware balanced work assignment + W-first staging.
//  * Real tiles (lt*64 < seqlen[b]) are enumerated via an unrolled register
//    prefix over the 16 batches and packed into the FIRST 2R dispatch slots,
//    preserving R13's same-XCD pairing (slots d and d+8 = the two col-halves
//    of one tile -> same slot mod 8 -> same XCD -> paired gather L2-hits).
//  * The masked zero-region is split exactly evenly across ALL 1024 blocks
//    (flat f32x4 indexing) -> no more random 2x makespan tail from whole
//    blocks being masked.
//  * W staged into LDS BEFORE the A-gather is issued, so its ds_writes don't
//    queue behind the 900cy gather loads in the in-order vmcnt stream.
// GEMM body otherwise identical to R13: 64tok x 64col-half, W-half
// fragment-major in 40KB LDS (conflict-free ds_read_b128), av[10] hoisted
// gather, exact-bounds tails, epilogue masks partial tiles.

#define E 300
#define P 128
#define S 2048
#define BS 32768
#define TM 64
#define NB 16

typedef short bf16x8 __attribute__((ext_vector_type(8)));
typedef short bf16x4 __attribute__((ext_vector_type(4)));
typedef float f32x4 __attribute__((ext_vector_type(4)));

__device__ inline unsigned short f32_bf16_fast(float f) {
    unsigned int u = __builtin_bit_cast(unsigned int, f);
    return (unsigned short)((u + 0x8000u) >> 16);
}
__device__ inline bf16x8 cvt8(f32x4 a, f32x4 b) {
    bf16x8 r;
    r[0] = (short)f32_bf16_fast(a[0]); r[1] = (short)f32_bf16_fast(a[1]);
    r[2] = (short)f32_bf16_fast(a[2]); r[3] = (short)f32_bf16_fast(a[3]);
    r[4] = (short)f32_bf16_fast(b[0]); r[5] = (short)f32_bf16_fast(b[1]);
    r[6] = (short)f32_bf16_fast(b[2]); r[7] = (short)f32_bf16_fast(b[3]);
    return r;
}
__device__ inline bf16x4 cvt4(f32x4 a) {
    bf16x4 r;
    r[0] = (short)f32_bf16_fast(a[0]); r[1] = (short)f32_bf16_fast(a[1]);
    r[2] = (short)f32_bf16_fast(a[2]); r[3] = (short)f32_bf16_fast(a[3]);
    return r;
}

__global__ __launch_bounds__(256) void ft_main(
    const int* __restrict__ ids, const int* __restrict__ seqlen,
    const float* __restrict__ embed, const float* __restrict__ Wf,
    const float* __restrict__ bias, float* __restrict__ out)
{
    __shared__ unsigned char Wl[40960];

    const int tid  = threadIdx.x;
    const int wave = tid >> 6, lane = tid & 63;
    const int fr   = lane & 15, kg = lane >> 4;
    const int d    = blockIdx.x;                 // [0, 1024)

    // slot -> (real-tile index rt, col-half ch); pair (d, d+8) same XCD
    const int grp = d >> 4, sub = d & 15;
    const int rt  = grp * 8 + (sub & 7);         // [0, 512)
    const int ch  = sub >> 3;

    // locate rt among real tiles: batch b, local tile lt (register-only scan)
    int b = -1, lt = 0, acc = 0;
    #pragma unroll
    for (int bb = 0; bb < NB; ++bb) {
        int rb = (seqlen[bb] + 63) >> 6;         // real tiles in batch bb
        if (rt >= acc && rt < acc + rb) { b = bb; lt = rt - acc; }
        acc += rb;
    }

    if (b >= 0) {                                 // ---- real GEMM block ----
        const int tok0 = (b << 11) + (lt << 6);
        const int sl0  = seqlen[b];

        // -- stage W rows [ch*64, ch*64+64) -> LDS bf16 fragment-major (FIRST) --
        const int R0 = ch * 64;
        #pragma unroll
        for (int i = 0; i < 20; ++i) {
            int g4 = tid + i * 256;               // [0, 5120) quads
            int r  = g4 / 80;
            int c4 = g4 - r * 80;
            int c0 = c4 * 4;                      // {0,4,...,316}
            f32x4 v = {0.f, 0.f, 0.f, 0.f};
            if (c0 < 300)                         // c0 <= 296: reads 296..299 exact
                v = *(const f32x4*)(Wf + (long long)(R0 + r) * E + c0);
            int s   = c0 >> 5;
            int kgg = (c0 & 31) >> 3;
            int h   = (c0 >> 2) & 1;
            int ni  = r >> 4;
            int fr2 = r & 15;
            int off = (((s * 4 + ni) * 16 + fr2) << 6) + (kgg << 4) + (h << 3);
            *(bf16x4*)(Wl + off) = cvt4(v);
        }

        // -- A: gather this lane's row fragments (19 independent loads) --
        const int token_a = tok0 + wave * 16 + fr;
        const int id = ids[token_a];
        const float* __restrict__ rp = embed + (long long)id * E;

        bf16x8 av[10];
        #pragma unroll
        for (int s = 0; s < 9; ++s) {
            const int kb = s * 32 + kg * 8;       // <= 280; ends 287 < 300
            f32x4 f0 = *(const f32x4*)(rp + kb);
            f32x4 f1 = *(const f32x4*)(rp + kb + 4);
            av[s] = cvt8(f0, f1);
        }
        {   // tail: valid k 288..299, exact bounds
            f32x4 z4 = {0.f, 0.f, 0.f, 0.f};
            f32x4 f0 = z4, f1 = z4;
            if (kg == 0)      { f0 = *(const f32x4*)(rp + 288); f1 = *(const f32x4*)(rp + 292); }
            else if (kg == 1) { f0 = *(const f32x4*)(rp + 296); }
            av[9] = cvt8(f0, f1);
        }
        __syncthreads();

        // -- MFMA: 10 k-steps x 4 ni, B from LDS (conflict-free b128) --
        f32x4 acc4[4];
        #pragma unroll
        for (int ni = 0; ni < 4; ++ni) acc4[ni] = (f32x4){0.f, 0.f, 0.f, 0.f};

        #pragma unroll
        for (int s = 0; s < 10; ++s) {
            #pragma unroll
            for (int ni = 0; ni < 4; ++ni) {
                bf16x8 bv = *(const bf16x8*)(Wl + ((((s * 4 + ni) * 16 + fr) << 6) + (kg << 4)));
                acc4[ni] = __builtin_amdgcn_mfma_f32_16x16x32_bf16(av[s], bv, acc4[ni], 0, 0, 0);
            }
        }

        // -- epilogue: +bias, per-row seq-mask, store --
        // C/D layout: col(=W row -> P) = lane&15, row(=token) = (lane>>4)*4 + j
        float bs[4];
        #pragma unroll
        for (int ni = 0; ni < 4; ++ni) bs[ni] = bias[ch * 64 + ni * 16 + fr];

        #pragma unroll
        for (int j = 0; j < 4; ++j) {
            int orow  = wave * 16 + kg * 4 + j;
            int token = tok0 + orow;
            int t     = token & (S - 1);
            bool valid = (t < sl0);
            #pragma unroll
            for (int ni = 0; ni < 4; ++ni) {
                float v = valid ? (acc4[ni][j] + bs[ni]) : 0.0f;
                out[(long long)token * P + ch * 64 + ni * 16 + fr] = v;
            }
        }
    }

    // ---- zero-fill share (ALL blocks, exactly even split) ----
    // masked region per batch: tokens [rb*64, 2048) -> (2048-rb*64)*32 quads
    int zp0 = 0, zp1, zp2, zp3, zp4, zp5, zp6, zp7, zp8,
        zp9, zp10, zp11, zp12, zp13, zp14, zp15, zp16;
    int rb0  = (seqlen[0]  + 63) >> 6,  rb1  = (seqlen[1]  + 63) >> 6,
        rb2  = (seqlen[2]  + 63) >> 6,  rb3  = (seqlen[3]  + 63) >> 6,
        rb4  = (seqlen[4]  + 63) >> 6,  rb5  = (seqlen[5]  + 63) >> 6,
        rb6  = (seqlen[6]  + 63) >> 6,  rb7  = (seqlen[7]  + 63) >> 6,
        rb8  = (seqlen[8]  + 63) >> 6,  rb9  = (seqlen[9]  + 63) >> 6,
        rb10 = (seqlen[10] + 63) >> 6,  rb11 = (seqlen[11] + 63) >> 6,
        rb12 = (seqlen[12] + 63) >> 6,  rb13 = (seqlen[13] + 63) >> 6,
        rb14 = (seqlen[14] + 63) >> 6,  rb15 = (seqlen[15] + 63) >> 6;
    zp1  = zp0  + ((S - (rb0  << 6)) << 5);
    zp2  = zp1  + ((S - (rb1  << 6)) << 5);
    zp3  = zp2  + ((S - (rb2  << 6)) << 5);
    zp4  = zp3  + ((S - (rb3  << 6)) << 5);
    zp5  = zp4  + ((S - (rb4  << 6)) << 5);
    zp6  = zp5  + ((S - (rb5  << 6)) << 5);
    zp7  = zp6  + ((S - (rb6  << 6)) << 5);
    zp8  = zp7  + ((S - (rb7  << 6)) << 5);
    zp9  = zp8  + ((S - (rb8  << 6)) << 5);
    zp10 = zp9  + ((S - (rb9  << 6)) << 5);
    zp11 = zp10 + ((S - (rb10 << 6)) << 5);
    zp12 = zp11 + ((S - (rb11 << 6)) << 5);
    zp13 = zp12 + ((S - (rb12 << 6)) << 5);
    zp14 = zp13 + ((S - (rb13 << 6)) << 5);
    zp15 = zp14 + ((S - (rb14 << 6)) << 5);
    zp16 = zp15 + ((S - (rb15 << 6)) << 5);

    const int zq  = zp16;
    const int per = (zq + 1023) >> 10;           // quads per block
    int q0 = d * per;
    int q1 = q0 + per; if (q1 > zq) q1 = zq;

    for (int q = q0 + tid; q < q1; q += 256) {
        // locate batch via register compare chain (no runtime-indexed arrays)
        int base = 0, tk0 = 0;
        #define ZSEL(BB, LO, HI, RB) \
            if (q >= (LO) && q < (HI)) { base = (LO); tk0 = ((BB) << 11) + ((RB) << 6); }
        ZSEL(0,  zp0,  zp1,  rb0)  ZSEL(1,  zp1,  zp2,  rb1)
        ZSEL(2,  zp2,  zp3,  rb2)  ZSEL(3,  zp3,  zp4,  rb3)
        ZSEL(4,  zp4,  zp5,  rb4)  ZSEL(5,  zp5,  zp6,  rb5)
        ZSEL(6,  zp6,  zp7,  rb6)  ZSEL(7,  zp7,  zp8,  rb7)
        ZSEL(8,  zp8,  zp9,  rb8)  ZSEL(9,  zp9,  zp10, rb9)
        ZSEL(10, zp10, zp11, rb10) ZSEL(11, zp11, zp12, rb11)
        ZSEL(12, zp12, zp13, rb12) ZSEL(13, zp13, zp14, rb13)
        ZSEL(14, zp14, zp15, rb14) ZSEL(15, zp15, zp16, rb15)
        #undef ZSEL
        int lq    = q - base;
        int token = tk0 + (lq >> 5);
        int c     = (lq & 31) << 2;
        *(f32x4*)(out + (long long)token * P + c) = (f32x4){0.f, 0.f, 0.f, 0.f};
    }
}

extern "C" void kernel_launch(void* const* d_in, const int* in_sizes, int n_in,
                              void* d_out, int out_size, void* d_ws, size_t ws_size,
                              hipStream_t stream) {
    const int*   ids    = (const int*)d_in[0];
    const int*   sl     = (const int*)d_in[1];
    const float* embed  = (const float*)d_in[2];
    const float* W      = (const float*)d_in[3];
    const float* bias   = (const float*)d_in[4];
    float*       out    = (float*)d_out;

    ft_main<<<(BS / TM) * 2, 256, 0, stream>>>(ids, sl, embed, W, bias, out);
}